// Round 3
// baseline (410.491 us; speedup 1.0000x reference)
//
#include <hip/hip_runtime.h>

#define N_TOT 10000
#define CLS_P 1000
#define NC 10
#define D 1024

#define TM 256                    // block tile (i and j)
#define NT2 40                    // ceil(10000/256)
#define NWG ((NT2 * (NT2 + 1)) / 2)   // 820 upper-tri tiles
#define KT 32                     // K-tiles of 32 (K = 1024)
#define DELTA 1.35e-5f
#define INV_SCALE2 4.8828125e-4f  // 2 / 4096  (Xh stores 64*x; acc = 4096*dot)
#define ESC_LOC 256

// LDS geometry, units = unsigned short (2B)
#define BUF_S 16384               // ring slot: A 8192 + B 8192 shorts (32 KB)
#define B_OFF 8192
#define HALF_S 4096               // half-tile: 128 rows * 32 shorts

typedef _Float16 f16x8 __attribute__((ext_vector_type(8)));
typedef float f32x4 __attribute__((ext_vector_type(4)));
typedef const __attribute__((address_space(1))) unsigned int* gptr_t;
typedef __attribute__((address_space(3))) unsigned int* lptr_t;

// ---------------- zero output ----------------
__global__ void zero_kernel(int* __restrict__ out, int n) {
    int i = blockIdx.x * blockDim.x + threadIdx.x;
    if (i < n) out[i] = 0;
}

// ---------------- gather + fp16(64x) + fp64 norms ----------------
__global__ void prep_kernel(const float* __restrict__ feats, const int* __restrict__ ids,
                            unsigned short* __restrict__ Xh,
                            double* __restrict__ sqd, float* __restrict__ sqf) {
    int row = blockIdx.x;
    int id = ids[row];
    const float4* rp = (const float4*)(feats + (size_t)id * D);
    float4 v = rp[threadIdx.x];  // 256 threads * 4 = 1024
    float f[4] = {v.x, v.y, v.z, v.w};
    ushort4 hv;
    unsigned short* hp = &hv.x;
    double s = 0.0;
    #pragma unroll
    for (int e = 0; e < 4; e++) {
        s += (double)f[e] * f[e];
        union { _Float16 h; unsigned short u; } cv;
        cv.h = (_Float16)(f[e] * 64.0f);   // RNE; x64 avoids fp16 denormals
        hp[e] = cv.u;
    }
    *(ushort4*)(Xh + (size_t)row * D + threadIdx.x * 4) = hv;

    #pragma unroll
    for (int off = 32; off > 0; off >>= 1)
        s += __shfl_down(s, off, 64);
    __shared__ double wsum[4];
    int lane = threadIdx.x & 63, wv = threadIdx.x >> 6;
    if (lane == 0) wsum[wv] = s;
    __syncthreads();
    if (threadIdx.x == 0) {
        double t = wsum[0] + wsum[1] + wsum[2] + wsum[3];
        sqd[row] = t;
        sqf[row] = (float)t;
    }
}

// ---------------- 256x256-tile 8-wave MFMA count kernel ----------------
// m201 8-phase template port: per K-tile = 2 phases, each
// {ds_reads for this cluster; 2 gload_lds; [vmcnt gate]; s_barrier; MFMA; s_barrier}.
// Reads issued BEFORE the leading barrier, consumed right after -> wave stagger
// lets one wave's MFMA cover other waves' LDS drain. vmcnt(8) counted, never 0.
__launch_bounds__(512, 2)
__global__ void count_kernel(const unsigned short* __restrict__ Xh,
                             const float* __restrict__ sqf,
                             const double* __restrict__ sqd,
                             const float* __restrict__ feats,
                             const int* __restrict__ ids,
                             int* __restrict__ counts) {
    // ---- bijective XCD-chunked swizzle ----
    int bid = blockIdx.x;
    {
        const int q = NWG >> 3, rr = NWG & 7;   // 102, 4
        int xcd = bid & 7, idx = bid >> 3;
        bid = (xcd < rr ? xcd * (q + 1) : rr * (q + 1) + (xcd - rr) * q) + idx;
    }
    // ---- triangular decode: bid -> (it, jt), it <= jt ----
    int it = 0, rem = bid;
    while (rem >= NT2 - it) { rem -= NT2 - it; ++it; }
    const int jt = it + rem;
    const int ib = it * TM, jb = jt * TM;

    // skip tiles that are entirely same-class
    {
        int i1 = ib + TM - 1; if (i1 > N_TOT - 1) i1 = N_TOT - 1;
        int j1 = jb + TM - 1; if (j1 > N_TOT - 1) j1 = N_TOT - 1;
        int ci0 = ib / CLS_P, ci1 = i1 / CLS_P;
        int cj0 = jb / CLS_P, cj1 = j1 / CLS_P;
        if (ci0 == ci1 && cj0 == cj1 && ci0 == cj0) return;
    }

    __shared__ unsigned short S[4 * BUF_S];   // 128 KB ring
    __shared__ int cred_i[TM], cred_j[TM];
    __shared__ int esc_n;
    __shared__ int2 esc_buf[ESC_LOC];

    const int tid = threadIdx.x;
    const int lane = tid & 63, w = tid >> 6;   // 8 waves
    const int wr = w >> 2, wc = w & 3;         // 2 (M) x 4 (N) wave grid
    const int quad = lane >> 4, col = lane & 15;

    if (tid == 0) esc_n = 0;

    // ---- staging setup: 512 thr x 16B = one 8KB half-tile per instruction ----
    // lane writes phys k-slot p=lane&3 of LDS row r; source k-quarter = (p - r - (r>>2)) & 3
    const int rl = lane >> 2;                  // row 0..15 within wave's 16-row chunk
    const int srow = (w << 4) + rl;            // row 0..127 within half
    const int swz = ((lane & 3) - rl - (rl >> 2)) & 3;
    int gA0 = ib + srow;         if (gA0 > N_TOT - 1) gA0 = N_TOT - 1;
    int gA1 = ib + 128 + srow;   if (gA1 > N_TOT - 1) gA1 = N_TOT - 1;
    int gB0 = jb + srow;         if (gB0 > N_TOT - 1) gB0 = N_TOT - 1;
    int gB1 = jb + 128 + srow;   if (gB1 > N_TOT - 1) gB1 = N_TOT - 1;
    const unsigned short* sA0 = Xh + (size_t)gA0 * D + swz * 8;
    const unsigned short* sA1 = Xh + (size_t)gA1 * D + swz * 8;
    const unsigned short* sB0 = Xh + (size_t)gB0 * D + swz * 8;
    const unsigned short* sB1 = Xh + (size_t)gB1 * D + swz * 8;
    const int wdst = w << 9;   // w * 512 shorts (wave's linear 1KB chunk)

#define STG_A(SLOT_, KS_) do {                                                         \
    __builtin_amdgcn_global_load_lds((gptr_t)(sA0 + (KS_)),                            \
        (lptr_t)(S + (SLOT_) * BUF_S + wdst), 16, 0, 0);                               \
    __builtin_amdgcn_global_load_lds((gptr_t)(sA1 + (KS_)),                            \
        (lptr_t)(S + (SLOT_) * BUF_S + HALF_S + wdst), 16, 0, 0);                      \
} while (0)
#define STG_B(SLOT_, KS_) do {                                                         \
    __builtin_amdgcn_global_load_lds((gptr_t)(sB0 + (KS_)),                            \
        (lptr_t)(S + (SLOT_) * BUF_S + B_OFF + wdst), 16, 0, 0);                       \
    __builtin_amdgcn_global_load_lds((gptr_t)(sB1 + (KS_)),                            \
        (lptr_t)(S + (SLOT_) * BUF_S + B_OFF + HALF_S + wdst), 16, 0, 0);              \
} while (0)

    // ---- fragment read offsets (shorts); reader quad q at row R uses phys slot
    //      (q + R + (R>>2)) & 3 = (q + col + (col>>2)) & 3.  Bank-balanced:
    //      each bank serves exactly 8 words per wave b128 read (theoretical min). ----
    const int sl = ((quad + col + (col >> 2)) & 3) << 3;
    const int aoff = (wr << 12) + (col << 5) + sl;             // + m*512
    const int boff = B_OFF + (wc << 11) + (col << 5) + sl;     // + n*512

    f32x4 acc[8][4];
    #pragma unroll
    for (int m = 0; m < 8; ++m)
        #pragma unroll
        for (int n = 0; n < 4; ++n)
            acc[m][n] = (f32x4){0.f, 0.f, 0.f, 0.f};

    f16x8 a[4], b[4], a2[4];

    // ---- prologue: stage kt 0,1,2 (12 loads); retire kt0; keep 8 in flight ----
    STG_A(0, 0);   STG_B(0, 0);
    STG_A(1, 32);  STG_B(1, 32);
    STG_A(2, 64);  STG_B(2, 64);
    asm volatile("s_waitcnt vmcnt(8)\ns_barrier" ::: "memory");

    // ---- main loop: 2 template phases per K-tile ----
    #pragma unroll 4
    for (int kt = 0; kt < KT; ++kt) {
        const unsigned short* bufp = S + (kt & 3) * BUF_S;
        const int s3 = (kt + 3) & 3;
        const int ks = ((kt + 3) & (KT - 1)) << 5;   // wraps to dummies for kt>=29 (dead slots)

        // ======== phase 1: top half ========
        #pragma unroll
        for (int m = 0; m < 4; ++m) a[m] = *(const f16x8*)(bufp + aoff + m * 512);
        #pragma unroll
        for (int n = 0; n < 4; ++n) b[n] = *(const f16x8*)(bufp + boff + n * 512);
        STG_A(s3, ks);
        asm volatile("s_barrier" ::: "memory");
        __builtin_amdgcn_sched_barrier(0);
        __builtin_amdgcn_s_setprio(1);
        #pragma unroll
        for (int m = 0; m < 4; ++m)
            #pragma unroll
            for (int n = 0; n < 4; ++n)
                acc[m][n] = __builtin_amdgcn_mfma_f32_16x16x32_f16(a[m], b[n], acc[m][n], 0, 0, 0);
        __builtin_amdgcn_s_setprio(0);
        __builtin_amdgcn_sched_barrier(0);
        asm volatile("s_barrier" ::: "memory");

        // ======== phase 2: bottom half (B reused from regs) ========
        #pragma unroll
        for (int m = 0; m < 4; ++m) a2[m] = *(const f16x8*)(bufp + aoff + 2048 + m * 512);
        STG_B(s3, ks);
        // counted gate: retire slot kt+1's 4 loads; keep kt+2 (4) + kt+3 (4) in flight
        asm volatile("s_waitcnt vmcnt(8)\ns_barrier" ::: "memory");
        __builtin_amdgcn_sched_barrier(0);
        __builtin_amdgcn_s_setprio(1);
        #pragma unroll
        for (int m = 0; m < 4; ++m)
            #pragma unroll
            for (int n = 0; n < 4; ++n)
                acc[4 + m][n] = __builtin_amdgcn_mfma_f32_16x16x32_f16(a2[m], b[n], acc[4 + m][n], 0, 0, 0);
        __builtin_amdgcn_s_setprio(0);
        __builtin_amdgcn_sched_barrier(0);
        asm volatile("s_barrier" ::: "memory");
    }

    // ---------------- epilogue: threshold + LDS-buffered escalate + symmetric reduce ----------------
    if (tid < TM) { cred_i[tid] = 0; cred_j[tid] = 0; }
    __syncthreads();

    const float thr_lo = 0.25f - DELTA;
    const float thr_hi = 0.25f + DELTA;
    const bool diag = (ib == jb);

    float sqj[4];
    int clsj[4], jidx[4], jv[4];
    #pragma unroll
    for (int n = 0; n < 4; ++n) {
        int j = jb + (wc << 6) + n * 16 + col;
        jidx[n] = j;
        jv[n] = (j < N_TOT);
        sqj[n] = jv[n] ? sqf[j] : 0.f;
        clsj[n] = j / CLS_P;
    }

    int cj[4] = {0, 0, 0, 0};

    #pragma unroll
    for (int m = 0; m < 8; ++m) {
        #pragma unroll
        for (int r = 0; r < 4; ++r) {
            int irow = (wr << 7) + m * 16 + quad * 4 + r;
            int i = ib + irow;
            bool iv = (i < N_TOT);
            float sqi = iv ? sqf[i] : 0.f;
            int clsi = i / CLS_P;
            int ci = 0;
            #pragma unroll
            for (int n = 0; n < 4; ++n) {
                int j = jidx[n];
                bool ok = iv && jv[n] && (clsj[n] != clsi) && (!diag || j > i);
                float d2 = sqi + sqj[n] - acc[m][n][r] * INV_SCALE2;
                bool in = ok && (d2 < thr_lo);
                bool esc = ok && !in && (d2 < thr_hi);
                ci += in ? 1 : 0;
                cj[n] += in ? 1 : 0;
                if (esc) {
                    int k = atomicAdd(&esc_n, 1);      // LDS atomic: fast
                    if (k < ESC_LOC) {
                        esc_buf[k] = make_int2(i, j);
                    } else {
                        // ~never: exact inline scalar fp64 check
                        const float* xi = feats + (size_t)ids[i] * D;
                        const float* xj = feats + (size_t)ids[j] * D;
                        double s = 0.0;
                        for (int kk = 0; kk < D; kk++) s += (double)xi[kk] * xj[kk];
                        if (sqd[i] + sqd[j] - 2.0 * s < 0.25) {
                            atomicAdd(&counts[i], 1);
                            atomicAdd(&counts[j], 1);
                        }
                    }
                }
            }
            ci += __shfl_xor(ci, 1, 64);
            ci += __shfl_xor(ci, 2, 64);
            ci += __shfl_xor(ci, 4, 64);
            ci += __shfl_xor(ci, 8, 64);
            if (col == 0 && ci) atomicAdd(&cred_i[irow], ci);
        }
    }
    #pragma unroll
    for (int n = 0; n < 4; ++n) {
        int v = cj[n];
        v += __shfl_xor(v, 16, 64);
        v += __shfl_xor(v, 32, 64);
        if (quad == 0 && v) atomicAdd(&cred_j[(wc << 6) + n * 16 + col], v);
    }
    __syncthreads();
    if (tid < TM) {
        int i = ib + tid;
        if (i < N_TOT && cred_i[tid]) atomicAdd(&counts[i], cred_i[tid]);
        int j = jb + tid;
        if (j < N_TOT && cred_j[tid]) atomicAdd(&counts[j], cred_j[tid]);
    }
    __syncthreads();   // esc_buf/esc_n visible to all waves

    // ---------------- fused fp64 escalation: 16 lanes/pair, 32 concurrent pairs ----------------
    int ne = esc_n; if (ne > ESC_LOC) ne = ESC_LOC;
    const int sub = lane >> 4, l16 = lane & 15;
    for (int p = w * 4 + sub; p < ne; p += 32) {
        int2 pr = esc_buf[p];
        const float* xi = feats + (size_t)ids[pr.x] * D;
        const float* xj = feats + (size_t)ids[pr.y] * D;
        double s = 0.0;
        int k0 = l16 * 64;
        #pragma unroll
        for (int k = 0; k < 64; k += 4) {
            float4 a4 = *(const float4*)(xi + k0 + k);
            float4 b4 = *(const float4*)(xj + k0 + k);
            s += (double)a4.x * b4.x + (double)a4.y * b4.y + (double)a4.z * b4.z + (double)a4.w * b4.w;
        }
        s += __shfl_xor(s, 1, 64);
        s += __shfl_xor(s, 2, 64);
        s += __shfl_xor(s, 4, 64);
        s += __shfl_xor(s, 8, 64);
        if (l16 == 0) {
            double d2 = sqd[pr.x] + sqd[pr.y] - 2.0 * s;
            if (d2 < 0.25) {
                atomicAdd(&counts[pr.x], 1);
                atomicAdd(&counts[pr.y], 1);
            }
        }
    }
}

// ---------------- stable-argsort selection (one thread per p) ----------------
__global__ void sel_kernel(const int* __restrict__ counts, const int* __restrict__ ids,
                           int* __restrict__ out_ids, int pcb) {
    int c = blockIdx.x;
    __shared__ int lc[CLS_P];
    for (int p = threadIdx.x; p < CLS_P; p += blockDim.x)
        lc[p] = counts[c * CLS_P + p];
    __syncthreads();
    int p = threadIdx.x;
    if (p < CLS_P) {
        int cp = lc[p];
        int rank = 0;
        for (int qq = 0; qq < CLS_P; qq++) {
            int cq = lc[qq];
            rank += (cq < cp) || (cq == cp && qq < p);
        }
        if (rank < pcb)
            out_ids[c * pcb + rank] = ids[c * CLS_P + p];
    }
}

extern "C" void kernel_launch(void* const* d_in, const int* in_sizes, int n_in,
                              void* d_out, int out_size, void* d_ws, size_t ws_size,
                              hipStream_t stream) {
    const float* feats = (const float*)d_in[0];
    const int* ids = (const int*)d_in[1];
    int budget = out_size - N_TOT;
    int pcb = budget / NC;  // 200
    int* out = (int*)d_out;
    int* counts_out = out + NC * pcb;

    char* ws = (char*)d_ws;
    const size_t XH_OFF = 0;
    const size_t SQD_OFF = XH_OFF + (size_t)N_TOT * D * 2;           // 20.48 MB
    const size_t SQF_OFF = SQD_OFF + (size_t)N_TOT * 8;

    unsigned short* Xh = (unsigned short*)(ws + XH_OFF);
    double* sqd = (double*)(ws + SQD_OFF);
    float* sqf = (float*)(ws + SQF_OFF);

    zero_kernel<<<(out_size + 255) / 256, 256, 0, stream>>>(out, out_size);
    prep_kernel<<<N_TOT, 256, 0, stream>>>(feats, ids, Xh, sqd, sqf);
    count_kernel<<<NWG, 512, 0, stream>>>(Xh, sqf, sqd, feats, ids, counts_out);
    sel_kernel<<<NC, 1024, 0, stream>>>(counts_out, ids, out, pcb);
}

// Round 4
// 359.589 us; speedup vs baseline: 1.1416x; 1.1416x over previous
//
#include <hip/hip_runtime.h>

#define N_TOT 10000
#define CLS_P 1000
#define NC 10
#define D 1024

#define TM 128            // block tile (i and j)
#define DELTA 1.35e-5f
#define INV_SCALE2 4.8828125e-4f   // 2 / 4096  (Xh stores 64*x; acc = 4096*dot)
#define ESC_LOC 256
#define KCHUNKS (D / 32)
#define NTILE ((N_TOT + TM - 1) / TM)   // 79

typedef _Float16 f16x8 __attribute__((ext_vector_type(8)));
typedef float f32x4 __attribute__((ext_vector_type(4)));
typedef const __attribute__((address_space(1))) unsigned int* gptr_t;
typedef __attribute__((address_space(3))) unsigned int* lptr_t;

// ---------------- zero output ----------------
__global__ void zero_kernel(int* __restrict__ out, int n) {
    int i = blockIdx.x * blockDim.x + threadIdx.x;
    if (i < n) out[i] = 0;
}

// ---------------- gather + fp16(64x) + fp64 norms ----------------
__global__ void prep_kernel(const float* __restrict__ feats, const int* __restrict__ ids,
                            unsigned short* __restrict__ Xh,
                            double* __restrict__ sqd, float* __restrict__ sqf) {
    int row = blockIdx.x;
    int id = ids[row];
    const float4* rp = (const float4*)(feats + (size_t)id * D);
    float4 v = rp[threadIdx.x];  // 256 threads * 4 = 1024
    float f[4] = {v.x, v.y, v.z, v.w};
    ushort4 hv;
    unsigned short* hp = &hv.x;
    double s = 0.0;
    #pragma unroll
    for (int e = 0; e < 4; e++) {
        s += (double)f[e] * f[e];
        union { _Float16 h; unsigned short u; } cv;
        cv.h = (_Float16)(f[e] * 64.0f);   // RNE; x64 avoids fp16 denormals
        hp[e] = cv.u;
    }
    *(ushort4*)(Xh + (size_t)row * D + threadIdx.x * 4) = hv;

    #pragma unroll
    for (int off = 32; off > 0; off >>= 1)
        s += __shfl_down(s, off, 64);
    __shared__ double wsum[4];
    int lane = threadIdx.x & 63, wv = threadIdx.x >> 6;
    if (lane == 0) wsum[wv] = s;
    __syncthreads();
    if (threadIdx.x == 0) {
        double t = wsum[0] + wsum[1] + wsum[2] + wsum[3];
        sqd[row] = t;
        sqf[row] = (float)t;
    }
}

// ---------------- fp16 MFMA pairwise count (2-buf async, 4 blocks/CU, fused fp64 escalation) ----------------
// 2-buffer m97-style schedule: STAGE(kc+1, other buf) -> MFMA(kc) -> vmcnt(0)+barrier
// -> FRAGS(kc+1).  LDS 35.3 KB/block -> 4 resident blocks/CU (was 3 at 51.5 KB):
// the extra independent barrier domain hides the per-chunk drain stall.
__launch_bounds__(256, 4)
__global__ void count_kernel(const unsigned short* __restrict__ Xh,
                             const float* __restrict__ sqf,
                             const double* __restrict__ sqd,
                             const float* __restrict__ feats,
                             const int* __restrict__ ids,
                             int* __restrict__ counts) {
    // ---- band swizzle: 8 i-tiles per band, j fastest -> L2-local working set ----
    int bid = blockIdx.y * gridDim.x + blockIdx.x;
    int it_t = 0, jt_t = 0;
    {
        int rem = bid, band = 0;
        while (true) {
            int h = NTILE - band * 8; if (h > 8) h = 8;
            int area = h * NTILE;
            if (rem < area) { it_t = band * 8 + rem % h; jt_t = rem / h; break; }
            rem -= area; band++;
        }
    }
    const int ib = it_t * TM, jb = jt_t * TM;
    if (jb < ib) return;  // symmetric: only upper triangle of tiles

    // skip tiles that are entirely same-class
    {
        int ci0 = ib / CLS_P, ci1 = (ib + TM - 1) / CLS_P;
        int cj0 = jb / CLS_P, cj1 = (jb + TM - 1) / CLS_P;
        if (ci0 == ci1 && cj0 == cj1 && ci0 == cj0) return;
    }

    // 2 buffers x (A 8KB + B 8KB) = 32 KB
    __shared__ unsigned short S[2 * 8192];
    __shared__ int cred_i[TM], cred_j[TM];
    __shared__ int esc_n;
    __shared__ int2 esc_buf[ESC_LOC];

    const int tid = threadIdx.x;
    const int lane = tid & 63, w = tid >> 6;
    const int wi = (w & 1) * 64, wj = (w >> 1) * 64;
    const int quad = lane >> 4, col = lane & 15;

    if (tid == 0) esc_n = 0;

    // staging: waves 0,1 -> A (rows of ib); waves 2,3 -> B (rows of jb)
    const int warr = w >> 1;
    const int w01 = w & 1;
    const int rl0 = lane >> 2;      // 0..15 row within 16-row call group
    const int slot = lane & 3;      // dest k-slot
    const int q = (slot - rl0 - (rl0 >> 2)) & 3;   // source k-quarter (swizzle)
    const int rowbase = warr ? jb : ib;

    const unsigned short* src[4];
    #pragma unroll
    for (int b = 0; b < 4; b++) {
        int grow = rowbase + b * 32 + w01 * 16 + rl0;
        if (grow > N_TOT - 1) grow = N_TOT - 1;
        src[b] = Xh + (size_t)grow * D + q * 8;
    }

#define STAGE(KC_, BUFBASE_)                                                     \
    {                                                                            \
        _Pragma("unroll")                                                        \
        for (int b = 0; b < 4; b++) {                                            \
            __builtin_amdgcn_global_load_lds(                                    \
                (gptr_t)(src[b] + (KC_) * 32),                                   \
                (lptr_t)((BUFBASE_) + warr * 4096 + b * 1024 + w01 * 512),       \
                16, 0, 0);                                                       \
        }                                                                        \
    }

#define FRAGS_(AH, BH, BUFBASE_)                                                 \
    {                                                                            \
        _Pragma("unroll")                                                        \
        for (int t = 0; t < 4; t++) {                                            \
            int rA = wi + t * 16 + col;                                          \
            int sA = (quad + rA + (rA >> 2)) & 3;                                \
            AH[t] = *(const f16x8*)((BUFBASE_) + rA * 32 + sA * 8);              \
            int rB = wj + t * 16 + col;                                          \
            int sB = (quad + rB + (rB >> 2)) & 3;                                \
            BH[t] = *(const f16x8*)((BUFBASE_) + 4096 + rB * 32 + sB * 8);       \
        }                                                                        \
    }

#define MFMA16_(AH, BH)                                                          \
    {                                                                            \
        _Pragma("unroll")                                                        \
        for (int it = 0; it < 4; it++)                                           \
            _Pragma("unroll")                                                    \
            for (int jt = 0; jt < 4; jt++)                                       \
                acc[it][jt] = __builtin_amdgcn_mfma_f32_16x16x32_f16(AH[it], BH[jt], acc[it][jt], 0, 0, 0); \
    }

#define WAIT0_BAR asm volatile("s_waitcnt vmcnt(0)\ns_barrier" ::: "memory")

    f32x4 acc[4][4];
    #pragma unroll
    for (int it = 0; it < 4; it++)
        #pragma unroll
        for (int jt = 0; jt < 4; jt++)
            acc[it][jt] = (f32x4){0.f, 0.f, 0.f, 0.f};

    f16x8 ah0[4], bh0[4];

    unsigned short* p0 = S;
    unsigned short* p1 = S + 8192;

    // prologue: stage kc0 into p0; drain; preload frags0
    STAGE(0, p0);
    WAIT0_BAR;
    FRAGS_(ah0, bh0, p0);

    // main: stage next into other buffer, compute current, drain+join, read next frags
    #pragma unroll 2
    for (int kc = 0; kc < KCHUNKS - 1; kc++) {
        unsigned short* nxt = (kc & 1) ? p0 : p1;
        STAGE(kc + 1, nxt);
        MFMA16_(ah0, bh0);
        WAIT0_BAR;
        FRAGS_(ah0, bh0, nxt);
    }
    MFMA16_(ah0, bh0);   // chunk 31

    // ---------------- epilogue: threshold + LDS-buffered escalate + symmetric reduce ----------------
    if (tid < TM) { cred_i[tid] = 0; cred_j[tid] = 0; }
    __syncthreads();

    const float thr_lo = 0.25f - DELTA;
    const float thr_hi = 0.25f + DELTA;
    const bool diag = (ib == jb);

    float sqj[4];
    int clsj[4], jv[4], jidx[4];
    #pragma unroll
    for (int jt = 0; jt < 4; jt++) {
        int j = jb + wj + jt * 16 + col;
        jidx[jt] = j;
        jv[jt] = (j < N_TOT);
        sqj[jt] = jv[jt] ? sqf[j] : 0.f;
        clsj[jt] = j / CLS_P;
    }

    int cj[4] = {0, 0, 0, 0};

    #pragma unroll
    for (int it = 0; it < 4; it++) {
        #pragma unroll
        for (int r = 0; r < 4; r++) {
            int irow = wi + it * 16 + quad * 4 + r;
            int i = ib + irow;
            bool iv = (i < N_TOT);
            float sqi = iv ? sqf[i] : 0.f;
            int clsi = i / CLS_P;
            int ci = 0;
            #pragma unroll
            for (int jt = 0; jt < 4; jt++) {
                int j = jidx[jt];
                bool ok = iv && jv[jt] && (clsj[jt] != clsi) && (!diag || j > i);
                float d2 = sqi + sqj[jt] - acc[it][jt][r] * INV_SCALE2;
                bool in = ok && (d2 < thr_lo);
                bool esc = ok && !in && (d2 < thr_hi);
                ci += in ? 1 : 0;
                cj[jt] += in ? 1 : 0;
                if (esc) {
                    int k = atomicAdd(&esc_n, 1);      // LDS atomic: fast
                    if (k < ESC_LOC) {
                        esc_buf[k] = make_int2(i, j);
                    } else {
                        // ~never (avg ~16/block, cap 256): exact inline scalar fp64 check
                        const float* xi = feats + (size_t)ids[i] * D;
                        const float* xj = feats + (size_t)ids[j] * D;
                        double s = 0.0;
                        for (int kk = 0; kk < D; kk++) s += (double)xi[kk] * xj[kk];
                        if (sqd[i] + sqd[j] - 2.0 * s < 0.25) {
                            atomicAdd(&counts[i], 1);
                            atomicAdd(&counts[j], 1);
                        }
                    }
                }
            }
            ci += __shfl_xor(ci, 1, 64);
            ci += __shfl_xor(ci, 2, 64);
            ci += __shfl_xor(ci, 4, 64);
            ci += __shfl_xor(ci, 8, 64);
            if (col == 0 && ci) atomicAdd(&cred_i[irow], ci);
        }
    }
    #pragma unroll
    for (int jt = 0; jt < 4; jt++) {
        int v = cj[jt];
        v += __shfl_xor(v, 16, 64);
        v += __shfl_xor(v, 32, 64);
        if (quad == 0 && v) atomicAdd(&cred_j[wj + jt * 16 + col], v);
    }
    __syncthreads();
    if (tid < TM) {
        int i = ib + tid;
        if (i < N_TOT && cred_i[tid]) atomicAdd(&counts[i], cred_i[tid]);
        int j = jb + tid;
        if (j < N_TOT && cred_j[tid]) atomicAdd(&counts[j], cred_j[tid]);
    }
    __syncthreads();   // esc_buf/esc_n visible to all waves

    // ---------------- fused fp64 escalation: 16 lanes/pair, 16 concurrent pairs ----------------
    int n = esc_n; if (n > ESC_LOC) n = ESC_LOC;
    const int sub = lane >> 4, l16 = lane & 15;
    for (int p = w * 4 + sub; p < n; p += 16) {
        int2 pr = esc_buf[p];
        const float* xi = feats + (size_t)ids[pr.x] * D;
        const float* xj = feats + (size_t)ids[pr.y] * D;
        double s = 0.0;
        int k0 = l16 * 64;
        #pragma unroll
        for (int k = 0; k < 64; k += 4) {
            float4 a = *(const float4*)(xi + k0 + k);
            float4 b = *(const float4*)(xj + k0 + k);
            s += (double)a.x * b.x + (double)a.y * b.y + (double)a.z * b.z + (double)a.w * b.w;
        }
        s += __shfl_xor(s, 1, 64);
        s += __shfl_xor(s, 2, 64);
        s += __shfl_xor(s, 4, 64);
        s += __shfl_xor(s, 8, 64);
        if (l16 == 0) {
            double d2 = sqd[pr.x] + sqd[pr.y] - 2.0 * s;
            if (d2 < 0.25) {
                atomicAdd(&counts[pr.x], 1);
                atomicAdd(&counts[pr.y], 1);
            }
        }
    }
}

// ---------------- stable-argsort selection (one thread per p) ----------------
__global__ void sel_kernel(const int* __restrict__ counts, const int* __restrict__ ids,
                           int* __restrict__ out_ids, int pcb) {
    int c = blockIdx.x;
    __shared__ int lc[CLS_P];
    for (int p = threadIdx.x; p < CLS_P; p += blockDim.x)
        lc[p] = counts[c * CLS_P + p];
    __syncthreads();
    int p = threadIdx.x;
    if (p < CLS_P) {
        int cp = lc[p];
        int rank = 0;
        for (int qq = 0; qq < CLS_P; qq++) {
            int cq = lc[qq];
            rank += (cq < cp) || (cq == cp && qq < p);
        }
        if (rank < pcb)
            out_ids[c * pcb + rank] = ids[c * CLS_P + p];
    }
}

extern "C" void kernel_launch(void* const* d_in, const int* in_sizes, int n_in,
                              void* d_out, int out_size, void* d_ws, size_t ws_size,
                              hipStream_t stream) {
    const float* feats = (const float*)d_in[0];
    const int* ids = (const int*)d_in[1];
    int budget = out_size - N_TOT;
    int pcb = budget / NC;  // 200
    int* out = (int*)d_out;
    int* counts_out = out + NC * pcb;

    char* ws = (char*)d_ws;
    const size_t XH_OFF = 0;
    const size_t SQD_OFF = XH_OFF + (size_t)N_TOT * D * 2;           // 20.48 MB
    const size_t SQF_OFF = SQD_OFF + (size_t)N_TOT * 8;

    unsigned short* Xh = (unsigned short*)(ws + XH_OFF);
    double* sqd = (double*)(ws + SQD_OFF);
    float* sqf = (float*)(ws + SQF_OFF);

    zero_kernel<<<(out_size + 255) / 256, 256, 0, stream>>>(out, out_size);
    prep_kernel<<<N_TOT, 256, 0, stream>>>(feats, ids, Xh, sqd, sqf);
    dim3 grid(NTILE, NTILE);
    count_kernel<<<grid, 256, 0, stream>>>(Xh, sqf, sqd, feats, ids, counts_out);
    sel_kernel<<<NC, 1024, 0, stream>>>(counts_out, ids, out, pcb);
}